// Round 5
// baseline (1360.589 us; speedup 1.0000x reference)
//
#include <hip/hip_runtime.h>
#include <math.h>

#define NPTS 4096
#define NB 2
#define K_TOTAL 12
#define BLOCK 256
#define TILE 128
#define NT 32
#define NCROSS (NB * NT * NT)        // 2048 cross tiles (C_xy, dual-use rows+cols)
#define NTRI (NT * (NT + 1) / 2)     // 528 upper-tri tiles per self matrix
#define NSELF (4 * NTRI)             // 2112 (C_xx,C_yy x 2 batches)
#define NWORK (NCROSS + NSELF)       // 4160 working tiles per step
#define GRID_TILES 2048              // 8 blocks/CU co-resident (LDS-limited fit)

// ws layout (floats):
//  [0..24)   sched: 12 x {eps, w}
//  [32..40)  Mbuf: per (pot,batch) stabilization max
//  [48]      tile counter (int), re-armed to GRID_TILES each step
//  [64..)    P: 4 pots x NB x NPTS; then V; then S
#define SCHED_OFF 0
#define MBUF_OFF 32
#define CNT_OFF 48
#define P_OFF 64
#define POT_SZ (4 * NB * NPTS)
#define V_OFF (P_OFF + POT_SZ)
#define S_OFF (V_OFF + POT_SZ)

#if __has_builtin(__builtin_amdgcn_exp2f)
#define EXP2F __builtin_amdgcn_exp2f
#else
#define EXP2F exp2f
#endif
#if __has_builtin(__builtin_amdgcn_logf)
#define LOG2F __builtin_amdgcn_logf
#else
#define LOG2F log2f
#endif
#if __has_builtin(__builtin_amdgcn_sqrtf)
#define FSQRTF __builtin_amdgcn_sqrtf
#else
#define FSQRTF sqrtf
#endif

#define BASE_LOGW -8.31776616671934f  // -log(4096), N==M
#define LOG2E 1.4426950408889634f
#define LN2 0.69314718055994531f

// ---------------------------------------------------------------------------
// Kernel A: zero P/S, V=1, Mbuf=base, counter=GRID_TILES. Diameter (f32,
// matching numpy) + eps schedule (f64, matching np.arange/np.exp).
// ---------------------------------------------------------------------------
__global__ __launch_bounds__(BLOCK) void k_init(
    const float2* __restrict__ x, const float2* __restrict__ y, float* ws)
{
  const int tid = threadIdx.x;
  for (int i = tid; i < POT_SZ; i += BLOCK) {
    ws[P_OFF + i] = 0.0f;
    ws[S_OFF + i] = 0.0f;
    ws[V_OFF + i] = 1.0f;
  }
  if (tid < 8) ws[MBUF_OFF + tid] = BASE_LOGW;
  if (tid == 0) *(int*)(ws + CNT_OFF) = GRID_TILES;

  float mnx = 1e30f, mny = 1e30f, mxx = -1e30f, mxy = -1e30f;
  for (int i = tid; i < NB * NPTS; i += BLOCK) {
    float2 p = x[i];
    mnx = fminf(mnx, p.x); mxx = fmaxf(mxx, p.x);
    mny = fminf(mny, p.y); mxy = fmaxf(mxy, p.y);
    float2 q = y[i];
    mnx = fminf(mnx, q.x); mxx = fmaxf(mxx, q.x);
    mny = fminf(mny, q.y); mxy = fmaxf(mxy, q.y);
  }
  for (int o = 32; o; o >>= 1) {
    mnx = fminf(mnx, __shfl_xor(mnx, o, 64));
    mxx = fmaxf(mxx, __shfl_xor(mxx, o, 64));
    mny = fminf(mny, __shfl_xor(mny, o, 64));
    mxy = fmaxf(mxy, __shfl_xor(mxy, o, 64));
  }
  __shared__ float r[4][4];
  const int wave = tid >> 6, lane = tid & 63;
  if (lane == 0) { r[0][wave] = mnx; r[1][wave] = mxx; r[2][wave] = mny; r[3][wave] = mxy; }
  __syncthreads();
  if (tid == 0) {
    mnx = fminf(fminf(r[0][0], r[0][1]), fminf(r[0][2], r[0][3]));
    mxx = fmaxf(fmaxf(r[1][0], r[1][1]), fmaxf(r[1][2], r[1][3]));
    mny = fminf(fminf(r[2][0], r[2][1]), fminf(r[2][2], r[2][3]));
    mxy = fmaxf(fmaxf(r[3][0], r[3][1]), fmaxf(r[3][2], r[3][3]));
    float rx = mxx - mnx, ry = mxy - mny;
    float dia = sqrtf(rx * rx + ry * ry);

    double a = log((double)dia);
    double stop = log(0.05);
    double stp = log(0.5);
    int cnt = (int)ceil((stop - a) / stp);  // data: cnt == 8
    if (cnt < 0) cnt = 0;
    if (cnt > K_TOTAL - 4) cnt = K_TOTAL - 4;

    float* sch = ws + SCHED_OFF;
    sch[0] = dia; sch[1] = 0.0f;   // init: direct assign at eps=diameter
    sch[2] = dia; sch[3] = 0.5f;   // annealing loop, w=0.5
    for (int k = 0; k < cnt; k++) {
      sch[2 * (2 + k)] = (float)exp(a + (double)k * stp);
      sch[2 * (2 + k) + 1] = 0.5f;
    }
    sch[2 * (2 + cnt)] = 0.05f; sch[2 * (2 + cnt) + 1] = 0.5f;
    for (int s = 3 + cnt; s < K_TOTAL - 1; s++) { sch[2 * s] = 0.05f; sch[2 * s + 1] = 1.0f; }
    sch[2 * (K_TOTAL - 1)] = 0.05f; sch[2 * (K_TOTAL - 1) + 1] = 0.0f;  // final extrapolation
  }
}

// ---------------------------------------------------------------------------
// Kernel B: persistent blocks; first tile = blockIdx.x (static), further
// tiles off a global counter whose atomicAdd is issued right after staging
// so its latency hides under the 64-pair compute. Two barriers per tile.
// Coordinates staged pre-scaled by log2e/eps: K = exp2(-sqrt(d2s)).
// Cross tiles feed row sums (f_ba) AND column sums (g_ab) from one K.
// Self tiles (symmetric) compute upper triangle only.
// Partial arrays padded to stride 129 -> 2-way bank aliasing (free).
// ---------------------------------------------------------------------------
__global__ __launch_bounds__(BLOCK, 8) void k_tiles(
    const float2* __restrict__ xpts, const float2* __restrict__ ypts,
    float* __restrict__ ws, int stepi)
{
  __shared__ float rXs[TILE], rYs[TILE], rVs[TILE];
  __shared__ float cXs[TILE], cYs[TILE], cVs[TILE];
  __shared__ float rowPart[16][129];
  __shared__ float colPart[16][129];
  __shared__ int sTile;

  const int tid = threadIdx.x;
  const float eps = ws[SCHED_OFF + 2 * stepi];
  const float scale = LOG2E / eps;
  int* cnt = (int*)(ws + CNT_OFF);
  float* V = ws + V_OFF;
  float* S = ws + S_OFF;

  int t = blockIdx.x;
  for (;;) {
    if (t >= NWORK) break;

    const float2 *rowp, *colp;
    const float *vrow, *vcol;
    float *srow, *scol;
    int ti, tj; bool dual;
    if (t < NCROSS) {
      const int b = t >> 10, r = t & 1023;
      ti = r >> 5; tj = r & 31;
      rowp = xpts + b * NPTS; colp = ypts + b * NPTS;
      vrow = V + (0 * NB + b) * NPTS; vcol = V + (1 * NB + b) * NPTS;
      srow = S + (0 * NB + b) * NPTS; scol = S + (1 * NB + b) * NPTS;
      dual = true;
    } else {
      const int t2 = t - NCROSS;
      const int m = t2 / NTRI;
      const int r = t2 - m * NTRI;
      int a = (int)((65.0 - sqrt(4225.0 - 8.0 * (double)r)) * 0.5);
      while (32 * (a + 1) - ((a + 1) * a) / 2 <= r) a++;
      while (32 * a - (a * (a - 1)) / 2 > r) a--;
      ti = a; tj = a + (r - (32 * a - (a * (a - 1)) / 2));
      const int mat = m >> 1, b = m & 1;
      const float2* pts = mat ? ypts : xpts;
      rowp = pts + b * NPTS; colp = rowp;
      const int p = 2 + mat;
      vrow = V + (p * NB + b) * NPTS; vcol = vrow;
      srow = S + (p * NB + b) * NPTS; scol = srow;
      dual = (ti != tj);
    }

    if (tid < TILE) {
      float2 pr = rowp[ti * TILE + tid];
      rXs[tid] = pr.x * scale; rYs[tid] = pr.y * scale;
      rVs[tid] = vrow[ti * TILE + tid];
    } else {
      const int k = tid - TILE;
      float2 pc = colp[tj * TILE + k];
      cXs[k] = pc.x * scale; cYs[k] = pc.y * scale;
      cVs[k] = vcol[tj * TILE + k];
    }
    __syncthreads();  // B1: staging visible; also fences prev tile's partial reads

    if (tid == 0) sTile = atomicAdd(cnt, 1);  // overlapped with compute below

    const int tx = tid & 15, ty = tid >> 4;
    float rx[8], ry[8], rv[8], cx[8], cy[8], cv[8], racc[8], cacc[8];
#pragma unroll
    for (int q = 0; q < 8; q++) {
      rx[q] = rXs[ty * 8 + q]; ry[q] = rYs[ty * 8 + q]; rv[q] = rVs[ty * 8 + q];
      cx[q] = cXs[tx * 8 + q]; cy[q] = cYs[tx * 8 + q]; cv[q] = cVs[tx * 8 + q];
      racc[q] = 0.0f; cacc[q] = 0.0f;
    }

#pragma unroll
    for (int q = 0; q < 8; q++) {
#pragma unroll
      for (int p = 0; p < 8; p++) {
        float dx = rx[q] - cx[p];
        float dy = ry[q] - cy[p];
        float K = EXP2F(-FSQRTF(fmaf(dx, dx, dy * dy)));
        racc[q] = fmaf(K, cv[p], racc[q]);
        cacc[p] = fmaf(K, rv[q], cacc[p]);
      }
    }

#pragma unroll
    for (int q = 0; q < 8; q++) {
      rowPart[tx][ty * 8 + q] = racc[q];
      colPart[ty][tx * 8 + q] = cacc[q];
    }
    __syncthreads();  // B2: partials visible; sTile visible

    if (tid < TILE) {
      float s = 0.0f;
#pragma unroll
      for (int u = 0; u < 16; u++) s += rowPart[u][tid];
      atomicAdd(&srow[ti * TILE + tid], s);
    } else if (dual) {
      const int k = tid - TILE;
      float s = 0.0f;
#pragma unroll
      for (int u = 0; u < 16; u++) s += colPart[u][k];
      atomicAdd(&scol[tj * TILE + k], s);
    }
    t = sTile;
    // next iteration's B1 fences these partial reads vs next partial writes
  }
}

// ---------------------------------------------------------------------------
// Kernel C: per (pot,batch): finalize f from S, mix with w, write P in place;
// build next step's V = exp2((logw + P/eps_next - Mnew)*log2e); zero S;
// block 0 re-arms the tile counter.
// ---------------------------------------------------------------------------
__global__ __launch_bounds__(BLOCK) void k_combine(float* __restrict__ ws, int stepi)
{
  const int pb = blockIdx.x;
  const int p = pb >> 1, b = pb & 1;
  const int tid = threadIdx.x;
  if (pb == 0 && tid == 0) *(int*)(ws + CNT_OFF) = GRID_TILES;

  const float eps = ws[SCHED_OFF + 2 * stepi];
  const float w = ws[SCHED_OFF + 2 * stepi + 1];
  int ni = stepi + 1; if (ni > K_TOTAL - 1) ni = K_TOTAL - 1;
  const float inv_eps_n = 1.0f / ws[SCHED_OFF + 2 * ni];
  const float Mh = ws[MBUF_OFF + pb];

  float* Pp = ws + P_OFF + (p * NB + b) * NPTS;
  float* Vp = ws + V_OFF + (p * NB + b) * NPTS;
  float* Sp = ws + S_OFF + (p * NB + b) * NPTS;

  float h[16];
  float lmax = -1e30f;
#pragma unroll
  for (int q = 0; q < 16; q++) {
    const int r = q * BLOCK + tid;
    float s = fmaxf(Sp[r], 1e-37f);
    float ft = -eps * fmaf(LN2, LOG2F(s), Mh);
    float fo = Pp[r];
    float fn = (w >= 1.0f) ? fo : fmaf(w, fo, (1.0f - w) * ft);
    Pp[r] = fn;
    Sp[r] = 0.0f;
    h[q] = fmaf(fn, inv_eps_n, BASE_LOGW);
    lmax = fmaxf(lmax, h[q]);
  }
  for (int o = 32; o; o >>= 1) lmax = fmaxf(lmax, __shfl_xor(lmax, o, 64));
  __shared__ float red[4];
  if ((tid & 63) == 0) red[tid >> 6] = lmax;
  __syncthreads();
  const float M = fmaxf(fmaxf(red[0], red[1]), fmaxf(red[2], red[3]));
#pragma unroll
  for (int q = 0; q < 16; q++) {
    const int r = q * BLOCK + tid;
    Vp[r] = EXP2F((h[q] - M) * LOG2E);
  }
  if (tid == 0) ws[MBUF_OFF + pb] = M;
}

// ---------------------------------------------------------------------------
// Kernel D: out = mean_b [ (1/N) sum(f_ba - f_aa) + (1/M) sum(g_ab - g_bb) ]
// ---------------------------------------------------------------------------
__global__ __launch_bounds__(BLOCK) void k_reduce(
    const float* __restrict__ pot, float* __restrict__ out)
{
  const int tid = threadIdx.x;
  double acc = 0.0;
  for (int i = tid; i < POT_SZ; i += BLOCK) {
    double v = (double)pot[i];
    acc += (i < 2 * NB * NPTS) ? v : -v;  // +f_ba +g_ab -f_aa -g_bb
  }
  for (int o = 32; o; o >>= 1) acc += __shfl_xor(acc, o, 64);
  __shared__ double rd[4];
  const int wave = tid >> 6, lane = tid & 63;
  if (lane == 0) rd[wave] = acc;
  __syncthreads();
  if (tid == 0) out[0] = (float)((rd[0] + rd[1] + rd[2] + rd[3]) / (double)(NB * NPTS));
}

extern "C" void kernel_launch(void* const* d_in, const int* in_sizes, int n_in,
                              void* d_out, int out_size, void* d_ws, size_t ws_size,
                              hipStream_t stream)
{
  const float2* x = (const float2*)d_in[0];  // pre (2,4096,2)
  const float2* y = (const float2*)d_in[1];  // gt  (2,4096,2)
  float* ws = (float*)d_ws;

  k_init<<<1, BLOCK, 0, stream>>>(x, y, ws);

  for (int s = 0; s < K_TOTAL; s++) {
    k_tiles<<<GRID_TILES, BLOCK, 0, stream>>>(x, y, ws, s);
    k_combine<<<8, BLOCK, 0, stream>>>(ws, s);
  }
  k_reduce<<<1, BLOCK, 0, stream>>>(ws + P_OFF, (float*)d_out);
}

// Round 6
// 760.705 us; speedup vs baseline: 1.7886x; 1.7886x over previous
//
#include <hip/hip_runtime.h>
#include <math.h>

#define NPTS 4096
#define NB 2
#define K_TOTAL 12
#define BLOCK 256
#define TILE 128
#define NT 32
#define NCROSS (NB * NT * NT)        // 2048 cross tiles (C_xy, dual-use rows+cols)
#define NTRI (NT * (NT + 1) / 2)     // 528 upper-tri tiles per self matrix
#define NSELF (4 * NTRI)             // 2112 (C_xx,C_yy x 2 batches)
#define NWORK (NCROSS + NSELF)       // 4160 working tiles per step
#define GRID_TILES 2048              // 8 blocks/CU co-resident (LDS/VGPR fit)

// ws layout (floats):
//  [0..24)   sched: 12 x {eps, w}
//  [32..40)  Mbuf: per (pot,batch) stabilization max
//  [48]      tile counter (int), re-armed to GRID_TILES each step
//  [64..)    P: 4 pots x NB x NPTS; then V; then S
#define SCHED_OFF 0
#define MBUF_OFF 32
#define CNT_OFF 48
#define P_OFF 64
#define POT_SZ (4 * NB * NPTS)
#define V_OFF (P_OFF + POT_SZ)
#define S_OFF (V_OFF + POT_SZ)

#if __has_builtin(__builtin_amdgcn_exp2f)
#define EXP2F __builtin_amdgcn_exp2f
#else
#define EXP2F exp2f
#endif
#if __has_builtin(__builtin_amdgcn_logf)
#define LOG2F __builtin_amdgcn_logf
#else
#define LOG2F log2f
#endif
#if __has_builtin(__builtin_amdgcn_sqrtf)
#define FSQRTF __builtin_amdgcn_sqrtf
#else
#define FSQRTF sqrtf
#endif

#define BASE_LOGW -8.31776616671934f  // -log(4096), N==M
#define LOG2E 1.4426950408889634f
#define LN2 0.69314718055994531f

// ---------------------------------------------------------------------------
// Kernel A: zero P/S, V=1, Mbuf=base, counter=GRID_TILES. Diameter (f32,
// matching numpy) + eps schedule (f64, matching np.arange/np.exp).
// ---------------------------------------------------------------------------
__global__ __launch_bounds__(BLOCK) void k_init(
    const float2* __restrict__ x, const float2* __restrict__ y, float* ws)
{
  const int tid = threadIdx.x;
  for (int i = tid; i < POT_SZ; i += BLOCK) {
    ws[P_OFF + i] = 0.0f;
    ws[S_OFF + i] = 0.0f;
    ws[V_OFF + i] = 1.0f;
  }
  if (tid < 8) ws[MBUF_OFF + tid] = BASE_LOGW;
  if (tid == 0) *(int*)(ws + CNT_OFF) = GRID_TILES;

  float mnx = 1e30f, mny = 1e30f, mxx = -1e30f, mxy = -1e30f;
  for (int i = tid; i < NB * NPTS; i += BLOCK) {
    float2 p = x[i];
    mnx = fminf(mnx, p.x); mxx = fmaxf(mxx, p.x);
    mny = fminf(mny, p.y); mxy = fmaxf(mxy, p.y);
    float2 q = y[i];
    mnx = fminf(mnx, q.x); mxx = fmaxf(mxx, q.x);
    mny = fminf(mny, q.y); mxy = fmaxf(mxy, q.y);
  }
  for (int o = 32; o; o >>= 1) {
    mnx = fminf(mnx, __shfl_xor(mnx, o, 64));
    mxx = fmaxf(mxx, __shfl_xor(mxx, o, 64));
    mny = fminf(mny, __shfl_xor(mny, o, 64));
    mxy = fmaxf(mxy, __shfl_xor(mxy, o, 64));
  }
  __shared__ float r[4][4];
  const int wave = tid >> 6, lane = tid & 63;
  if (lane == 0) { r[0][wave] = mnx; r[1][wave] = mxx; r[2][wave] = mny; r[3][wave] = mxy; }
  __syncthreads();
  if (tid == 0) {
    mnx = fminf(fminf(r[0][0], r[0][1]), fminf(r[0][2], r[0][3]));
    mxx = fmaxf(fmaxf(r[1][0], r[1][1]), fmaxf(r[1][2], r[1][3]));
    mny = fminf(fminf(r[2][0], r[2][1]), fminf(r[2][2], r[2][3]));
    mxy = fmaxf(fmaxf(r[3][0], r[3][1]), fmaxf(r[3][2], r[3][3]));
    float rx = mxx - mnx, ry = mxy - mny;
    float dia = sqrtf(rx * rx + ry * ry);

    double a = log((double)dia);
    double stop = log(0.05);
    double stp = log(0.5);
    int cnt = (int)ceil((stop - a) / stp);  // data: cnt == 8
    if (cnt < 0) cnt = 0;
    if (cnt > K_TOTAL - 4) cnt = K_TOTAL - 4;

    float* sch = ws + SCHED_OFF;
    sch[0] = dia; sch[1] = 0.0f;   // init: direct assign at eps=diameter
    sch[2] = dia; sch[3] = 0.5f;   // annealing loop, w=0.5
    for (int k = 0; k < cnt; k++) {
      sch[2 * (2 + k)] = (float)exp(a + (double)k * stp);
      sch[2 * (2 + k) + 1] = 0.5f;
    }
    sch[2 * (2 + cnt)] = 0.05f; sch[2 * (2 + cnt) + 1] = 0.5f;
    for (int s = 3 + cnt; s < K_TOTAL - 1; s++) { sch[2 * s] = 0.05f; sch[2 * s + 1] = 1.0f; }
    sch[2 * (K_TOTAL - 1)] = 0.05f; sch[2 * (K_TOTAL - 1) + 1] = 0.0f;  // final extrapolation
  }
}

// ---------------------------------------------------------------------------
// Kernel B: persistent blocks; first tile = blockIdx.x (static), further
// tiles off a global counter whose atomicAdd is issued right after staging
// so its latency hides under the 64-pair compute. Two barriers per tile.
// Coordinates staged pre-scaled by log2e/eps: K = exp2(-sqrt(d2s)).
// Cross tiles feed row sums (f_ba) AND column sums (g_ab) from one K.
// Self tiles (symmetric) compute upper triangle only.
// __launch_bounds__(256,4): caps VGPR at 128; compiler lands ~60 which gives
// 8 waves/SIMD naturally. (256,8) forced a 64-VGPR cap -> scratch spill ->
// 260 MB/dispatch of HBM spill traffic (round-5 regression). DO NOT raise.
// ---------------------------------------------------------------------------
__global__ __launch_bounds__(BLOCK, 4) void k_tiles(
    const float2* __restrict__ xpts, const float2* __restrict__ ypts,
    float* __restrict__ ws, int stepi)
{
  __shared__ float rXs[TILE], rYs[TILE], rVs[TILE];
  __shared__ float cXs[TILE], cYs[TILE], cVs[TILE];
  __shared__ float rowPart[16][129];
  __shared__ float colPart[16][129];
  __shared__ int sTile;

  const int tid = threadIdx.x;
  const float eps = ws[SCHED_OFF + 2 * stepi];
  const float scale = LOG2E / eps;
  int* cnt = (int*)(ws + CNT_OFF);
  float* V = ws + V_OFF;
  float* S = ws + S_OFF;

  int t = blockIdx.x;
  for (;;) {
    if (t >= NWORK) break;

    const float2 *rowp, *colp;
    const float *vrow, *vcol;
    float *srow, *scol;
    int ti, tj; bool dual;
    if (t < NCROSS) {
      const int b = t >> 10, r = t & 1023;
      ti = r >> 5; tj = r & 31;
      rowp = xpts + b * NPTS; colp = ypts + b * NPTS;
      vrow = V + (0 * NB + b) * NPTS; vcol = V + (1 * NB + b) * NPTS;
      srow = S + (0 * NB + b) * NPTS; scol = S + (1 * NB + b) * NPTS;
      dual = true;
    } else {
      const int t2 = t - NCROSS;
      const int m = t2 / NTRI;
      const int r = t2 - m * NTRI;
      int a = (int)((65.0 - sqrt(4225.0 - 8.0 * (double)r)) * 0.5);
      while (32 * (a + 1) - ((a + 1) * a) / 2 <= r) a++;
      while (32 * a - (a * (a - 1)) / 2 > r) a--;
      ti = a; tj = a + (r - (32 * a - (a * (a - 1)) / 2));
      const int mat = m >> 1, b = m & 1;
      const float2* pts = mat ? ypts : xpts;
      rowp = pts + b * NPTS; colp = rowp;
      const int p = 2 + mat;
      vrow = V + (p * NB + b) * NPTS; vcol = vrow;
      srow = S + (p * NB + b) * NPTS; scol = srow;
      dual = (ti != tj);
    }

    if (tid < TILE) {
      float2 pr = rowp[ti * TILE + tid];
      rXs[tid] = pr.x * scale; rYs[tid] = pr.y * scale;
      rVs[tid] = vrow[ti * TILE + tid];
    } else {
      const int k = tid - TILE;
      float2 pc = colp[tj * TILE + k];
      cXs[k] = pc.x * scale; cYs[k] = pc.y * scale;
      cVs[k] = vcol[tj * TILE + k];
    }
    __syncthreads();  // B1: staging visible; fences prev tile's partial reads

    if (tid == 0) sTile = atomicAdd(cnt, 1);  // latency hides under compute

    const int tx = tid & 15, ty = tid >> 4;
    float rx[8], ry[8], rv[8], cx[8], cy[8], cv[8], racc[8], cacc[8];
#pragma unroll
    for (int q = 0; q < 8; q++) {
      rx[q] = rXs[ty * 8 + q]; ry[q] = rYs[ty * 8 + q]; rv[q] = rVs[ty * 8 + q];
      cx[q] = cXs[tx * 8 + q]; cy[q] = cYs[tx * 8 + q]; cv[q] = cVs[tx * 8 + q];
      racc[q] = 0.0f; cacc[q] = 0.0f;
    }

#pragma unroll
    for (int q = 0; q < 8; q++) {
#pragma unroll
      for (int p = 0; p < 8; p++) {
        float dx = rx[q] - cx[p];
        float dy = ry[q] - cy[p];
        float K = EXP2F(-FSQRTF(fmaf(dx, dx, dy * dy)));
        racc[q] = fmaf(K, cv[p], racc[q]);
        cacc[p] = fmaf(K, rv[q], cacc[p]);
      }
    }

#pragma unroll
    for (int q = 0; q < 8; q++) {
      rowPart[tx][ty * 8 + q] = racc[q];
      colPart[ty][tx * 8 + q] = cacc[q];
    }
    __syncthreads();  // B2: partials visible; sTile visible

    if (tid < TILE) {
      float s = 0.0f;
#pragma unroll
      for (int u = 0; u < 16; u++) s += rowPart[u][tid];
      atomicAdd(&srow[ti * TILE + tid], s);
    } else if (dual) {
      const int k = tid - TILE;
      float s = 0.0f;
#pragma unroll
      for (int u = 0; u < 16; u++) s += colPart[u][k];
      atomicAdd(&scol[tj * TILE + k], s);
    }
    t = sTile;
    // next iteration's B1 fences these partial reads vs next partial writes
  }
}

// ---------------------------------------------------------------------------
// Kernel C: per (pot,batch): finalize f from S, mix with w, write P in place;
// build next step's V = exp2((logw + P/eps_next - Mnew)*log2e); zero S;
// block 0 re-arms the tile counter.
// ---------------------------------------------------------------------------
__global__ __launch_bounds__(BLOCK) void k_combine(float* __restrict__ ws, int stepi)
{
  const int pb = blockIdx.x;
  const int p = pb >> 1, b = pb & 1;
  const int tid = threadIdx.x;
  if (pb == 0 && tid == 0) *(int*)(ws + CNT_OFF) = GRID_TILES;

  const float eps = ws[SCHED_OFF + 2 * stepi];
  const float w = ws[SCHED_OFF + 2 * stepi + 1];
  int ni = stepi + 1; if (ni > K_TOTAL - 1) ni = K_TOTAL - 1;
  const float inv_eps_n = 1.0f / ws[SCHED_OFF + 2 * ni];
  const float Mh = ws[MBUF_OFF + pb];

  float* Pp = ws + P_OFF + (p * NB + b) * NPTS;
  float* Vp = ws + V_OFF + (p * NB + b) * NPTS;
  float* Sp = ws + S_OFF + (p * NB + b) * NPTS;

  float h[16];
  float lmax = -1e30f;
#pragma unroll
  for (int q = 0; q < 16; q++) {
    const int r = q * BLOCK + tid;
    float s = fmaxf(Sp[r], 1e-37f);
    float ft = -eps * fmaf(LN2, LOG2F(s), Mh);
    float fo = Pp[r];
    float fn = (w >= 1.0f) ? fo : fmaf(w, fo, (1.0f - w) * ft);
    Pp[r] = fn;
    Sp[r] = 0.0f;
    h[q] = fmaf(fn, inv_eps_n, BASE_LOGW);
    lmax = fmaxf(lmax, h[q]);
  }
  for (int o = 32; o; o >>= 1) lmax = fmaxf(lmax, __shfl_xor(lmax, o, 64));
  __shared__ float red[4];
  if ((tid & 63) == 0) red[tid >> 6] = lmax;
  __syncthreads();
  const float M = fmaxf(fmaxf(red[0], red[1]), fmaxf(red[2], red[3]));
#pragma unroll
  for (int q = 0; q < 16; q++) {
    const int r = q * BLOCK + tid;
    Vp[r] = EXP2F((h[q] - M) * LOG2E);
  }
  if (tid == 0) ws[MBUF_OFF + pb] = M;
}

// ---------------------------------------------------------------------------
// Kernel D: out = mean_b [ (1/N) sum(f_ba - f_aa) + (1/M) sum(g_ab - g_bb) ]
// ---------------------------------------------------------------------------
__global__ __launch_bounds__(BLOCK) void k_reduce(
    const float* __restrict__ pot, float* __restrict__ out)
{
  const int tid = threadIdx.x;
  double acc = 0.0;
  for (int i = tid; i < POT_SZ; i += BLOCK) {
    double v = (double)pot[i];
    acc += (i < 2 * NB * NPTS) ? v : -v;  // +f_ba +g_ab -f_aa -g_bb
  }
  for (int o = 32; o; o >>= 1) acc += __shfl_xor(acc, o, 64);
  __shared__ double rd[4];
  const int wave = tid >> 6, lane = tid & 63;
  if (lane == 0) rd[wave] = acc;
  __syncthreads();
  if (tid == 0) out[0] = (float)((rd[0] + rd[1] + rd[2] + rd[3]) / (double)(NB * NPTS));
}

extern "C" void kernel_launch(void* const* d_in, const int* in_sizes, int n_in,
                              void* d_out, int out_size, void* d_ws, size_t ws_size,
                              hipStream_t stream)
{
  const float2* x = (const float2*)d_in[0];  // pre (2,4096,2)
  const float2* y = (const float2*)d_in[1];  // gt  (2,4096,2)
  float* ws = (float*)d_ws;

  k_init<<<1, BLOCK, 0, stream>>>(x, y, ws);

  for (int s = 0; s < K_TOTAL; s++) {
    k_tiles<<<GRID_TILES, BLOCK, 0, stream>>>(x, y, ws, s);
    k_combine<<<8, BLOCK, 0, stream>>>(ws, s);
  }
  k_reduce<<<1, BLOCK, 0, stream>>>(ws + P_OFF, (float*)d_out);
}